// Round 6
// baseline (371.416 us; speedup 1.0000x reference)
//
#include <hip/hip_runtime.h>
#include <hip/hip_cooperative_groups.h>

namespace cg = cooperative_groups;

#define NUM_NODES 10000
#define NUM_EDGES 320000
#define FEAT_DIM  256
#define OVF_CAP   4096   // overflow edge slots (paranoia; expected 0 used)
#define GRID_BLKS 1024   // 4 blocks/CU x 256 CU -> guaranteed co-resident
#define BLOCK     256

typedef float f32x4 __attribute__((ext_vector_type(4)));

// ws layout:
//   int cursor[NUM_NODES]       -- per-node degree counters
//   int ovf_cnt                 -- overflow counter
//   int ovf[2*OVF_CAP]          -- (edge, node) overflow pairs
//   int buckets[NUM_NODES*cap]  -- per-node edge-id lists

__device__ __forceinline__ f32x4 nt_load4(const f32x4* p) {
    return __builtin_nontemporal_load(p);
}

// gather one node's row: wave of 64 lanes, lane owns one float4 of 256 floats
__device__ __forceinline__ void gather_node(
    const f32x4* __restrict__ msg4,
    const int*   __restrict__ cursor,
    const int*   __restrict__ buckets,
    f32x4*       __restrict__ out4,
    int cap, int n, int lane)
{
    int deg = cursor[n];
    if (deg > cap) deg = cap;
    const int* bl = buckets + (size_t)n * cap;

    f32x4 acc = (f32x4)(0.f);

    int m1  = deg < 64 ? deg : 64;
    int e_l = (lane < m1) ? bl[lane] : 0;
    int i = 0;
    for (; i + 8 <= m1; i += 8) {
        int e0 = __shfl(e_l, i),     e1 = __shfl(e_l, i + 1);
        int e2 = __shfl(e_l, i + 2), e3 = __shfl(e_l, i + 3);
        int e4 = __shfl(e_l, i + 4), e5 = __shfl(e_l, i + 5);
        int e6 = __shfl(e_l, i + 6), e7 = __shfl(e_l, i + 7);
        f32x4 v0 = nt_load4(msg4 + (size_t)e0 * 64 + lane);
        f32x4 v1 = nt_load4(msg4 + (size_t)e1 * 64 + lane);
        f32x4 v2 = nt_load4(msg4 + (size_t)e2 * 64 + lane);
        f32x4 v3 = nt_load4(msg4 + (size_t)e3 * 64 + lane);
        f32x4 v4 = nt_load4(msg4 + (size_t)e4 * 64 + lane);
        f32x4 v5 = nt_load4(msg4 + (size_t)e5 * 64 + lane);
        f32x4 v6 = nt_load4(msg4 + (size_t)e6 * 64 + lane);
        f32x4 v7 = nt_load4(msg4 + (size_t)e7 * 64 + lane);
        acc += ((v0 + v1) + (v2 + v3)) + ((v4 + v5) + (v6 + v7));
    }
    for (; i + 4 <= m1; i += 4) {
        int e0 = __shfl(e_l, i),     e1 = __shfl(e_l, i + 1);
        int e2 = __shfl(e_l, i + 2), e3 = __shfl(e_l, i + 3);
        f32x4 v0 = nt_load4(msg4 + (size_t)e0 * 64 + lane);
        f32x4 v1 = nt_load4(msg4 + (size_t)e1 * 64 + lane);
        f32x4 v2 = nt_load4(msg4 + (size_t)e2 * 64 + lane);
        f32x4 v3 = nt_load4(msg4 + (size_t)e3 * 64 + lane);
        acc += (v0 + v1) + (v2 + v3);
    }
    for (; i < m1; ++i) {
        int e = __shfl(e_l, i);
        acc += nt_load4(msg4 + (size_t)e * 64 + lane);
    }
    if (deg > 64) {                       // only possible when cap==128; rare
        int m2   = deg - 64;
        int e_l2 = (lane < m2) ? bl[64 + lane] : 0;
        for (int j = 0; j < m2; ++j) {
            int e = __shfl(e_l2, j);
            acc += nt_load4(msg4 + (size_t)e * 64 + lane);
        }
    }

    __builtin_nontemporal_store(acc, out4 + (size_t)n * 64 + lane);
}

// ---------------- fused cooperative kernel (one dispatch) ----------------
__global__ __launch_bounds__(BLOCK, 4) void fused_all(
    const f32x4* __restrict__ msg4,
    const float* __restrict__ msg,
    const int*   __restrict__ tgt,
    int*         __restrict__ cursor,
    int*         __restrict__ buckets,
    int          cap,
    int*         __restrict__ ovf_cnt,
    int*         __restrict__ ovf,
    f32x4*       __restrict__ out4,
    float*       __restrict__ out)
{
    cg::grid_group grid = cg::this_grid();
    const int tid = blockIdx.x * BLOCK + threadIdx.x;

    // phase 0: zero cursor[NUM_NODES] + ovf_cnt (adjacent)
    for (int i = tid; i < NUM_NODES + 1; i += GRID_BLKS * BLOCK) cursor[i] = 0;
    grid.sync();

    // phase 1: bucket edge ids (4 edges/thread, vectorized tgt read)
    for (int base = tid * 4; base < NUM_EDGES; base += GRID_BLKS * BLOCK * 4) {
        int4 t4 = *(const int4*)(tgt + base);
        int ts[4] = {t4.x, t4.y, t4.z, t4.w};
        #pragma unroll
        for (int k = 0; k < 4; ++k) {
            int e = base + k;
            int t = ts[k];
            int idx = atomicAdd(&cursor[t], 1);
            if (idx < cap) {
                buckets[(size_t)t * cap + idx] = e;
            } else {
                int o = atomicAdd(ovf_cnt, 1);
                if (o < OVF_CAP) { ovf[2 * o] = e; ovf[2 * o + 1] = t; }
            }
        }
    }
    grid.sync();

    // phase 2: gather, one wave per node (writes every row -> no out pre-zero)
    {
        int g    = threadIdx.x >> 6;
        int lane = threadIdx.x & 63;
        for (int n = blockIdx.x * 4 + g; n < NUM_NODES; n += GRID_BLKS * 4)
            gather_node(msg4, cursor, buckets, out4, cap, n, lane);
    }
    grid.sync();

    // phase 3: overflow cleanup (expected 0 entries)
    {
        int cnt = *ovf_cnt;
        if (cnt > OVF_CAP) cnt = OVF_CAP;
        for (int o = blockIdx.x; o < cnt; o += GRID_BLKS) {
            int e = ovf[2 * o], t = ovf[2 * o + 1];
            const float* m  = msg + (size_t)e * FEAT_DIM;
            float*       op = out + (size_t)t * FEAT_DIM;
            for (int f = threadIdx.x; f < FEAT_DIM; f += BLOCK)
                atomicAdd(op + f, m[f]);
        }
    }
}

// ---------------- fallback multi-dispatch path (proven, 95.8 us) ----------------
__global__ __launch_bounds__(256) void fill_buckets(
    const int* __restrict__ tgt, int* __restrict__ cursor, int* __restrict__ buckets,
    int cap, int* __restrict__ ovf_cnt, int* __restrict__ ovf)
{
    int base = (blockIdx.x * blockDim.x + threadIdx.x) * 4;
    if (base >= NUM_EDGES) return;
    int4 t4 = *(const int4*)(tgt + base);
    int ts[4] = {t4.x, t4.y, t4.z, t4.w};
    #pragma unroll
    for (int k = 0; k < 4; ++k) {
        int e = base + k;
        int t = ts[k];
        int idx = atomicAdd(&cursor[t], 1);
        if (idx < cap) {
            buckets[(size_t)t * cap + idx] = e;
        } else {
            int o = atomicAdd(ovf_cnt, 1);
            if (o < OVF_CAP) { ovf[2 * o] = e; ovf[2 * o + 1] = t; }
        }
    }
}

__global__ __launch_bounds__(256) void gather_sum(
    const f32x4* __restrict__ msg4, const int* __restrict__ cursor,
    const int* __restrict__ buckets, f32x4* __restrict__ out4, int cap)
{
    int g    = threadIdx.x >> 6;
    int lane = threadIdx.x & 63;
    int n    = blockIdx.x * 4 + g;
    if (n >= NUM_NODES) return;
    gather_node(msg4, cursor, buckets, out4, cap, n, lane);
}

__global__ __launch_bounds__(256) void ovf_cleanup(
    const float* __restrict__ msg, float* __restrict__ out,
    const int* __restrict__ ovf_cnt, const int* __restrict__ ovf)
{
    int cnt = *ovf_cnt;
    if (cnt > OVF_CAP) cnt = OVF_CAP;
    for (int o = blockIdx.x; o < cnt; o += gridDim.x) {
        int e = ovf[2 * o], t = ovf[2 * o + 1];
        const float* m  = msg + (size_t)e * FEAT_DIM;
        float*       op = out + (size_t)t * FEAT_DIM;
        for (int f = threadIdx.x; f < FEAT_DIM; f += blockDim.x)
            atomicAdd(op + f, m[f]);
    }
}

// last-resort fallback if ws is unexpectedly small (round-0 kernel)
__global__ __launch_bounds__(256) void scatter_add_kernel(
    const float4* __restrict__ msg4, const int* __restrict__ tgt, float* __restrict__ out)
{
    int idx = blockIdx.x * blockDim.x + threadIdx.x;
    int e  = idx >> 6;
    int f4 = idx & 63;
    if (e >= NUM_EDGES) return;
    float4 v = msg4[(size_t)e * 64 + f4];
    int t = tgt[e];
    float* o = out + (size_t)t * FEAT_DIM + f4 * 4;
    atomicAdd(o + 0, v.x);
    atomicAdd(o + 1, v.y);
    atomicAdd(o + 2, v.z);
    atomicAdd(o + 3, v.w);
}

extern "C" void kernel_launch(void* const* d_in, const int* in_sizes, int n_in,
                              void* d_out, int out_size, void* d_ws, size_t ws_size,
                              hipStream_t stream) {
    const float* msg  = (const float*)d_in[0];
    const f32x4* msg4 = (const f32x4*)d_in[0];
    const int*   eidx = (const int*)d_in[1];   // [2, NUM_EDGES] row-major int32
    const int*   tgt  = eidx + NUM_EDGES;      // edge_index[1]
    float*       out  = (float*)d_out;

    const size_t header = ((size_t)NUM_NODES + 1 + 2 * OVF_CAP) * sizeof(int);

    int cap = 0;
    if (ws_size > header) {
        size_t avail = (ws_size - header) / ((size_t)NUM_NODES * sizeof(int));
        cap = avail >= 128 ? 128 : (avail >= 64 ? 64 : 0);
    }

    if (cap > 0) {
        int* cursor  = (int*)d_ws;
        int* ovf_cnt = cursor + NUM_NODES;
        int* ovf     = ovf_cnt + 1;
        int* buckets = ovf + 2 * OVF_CAP;
        f32x4* out4  = (f32x4*)out;

        void* args[] = { (void*)&msg4, (void*)&msg, (void*)&tgt,
                         (void*)&cursor, (void*)&buckets, (void*)&cap,
                         (void*)&ovf_cnt, (void*)&ovf, (void*)&out4, (void*)&out };
        hipError_t err = hipLaunchCooperativeKernel(
            (const void*)fused_all, dim3(GRID_BLKS), dim3(BLOCK), args, 0, stream);

        if (err != hipSuccess) {
            // fallback: proven 4-dispatch path
            (void)hipMemsetAsync(cursor, 0, ((size_t)NUM_NODES + 1) * sizeof(int), stream);
            fill_buckets<<<(NUM_EDGES / 4 + 255) / 256, 256, 0, stream>>>(
                tgt, cursor, buckets, cap, ovf_cnt, ovf);
            gather_sum<<<NUM_NODES / 4, 256, 0, stream>>>(
                msg4, cursor, buckets, out4, cap);
            ovf_cleanup<<<8, 256, 0, stream>>>(msg, out, ovf_cnt, ovf);
        }
    } else {
        (void)hipMemsetAsync(out, 0, (size_t)out_size * sizeof(float), stream);
        const int total = NUM_EDGES * 64;
        scatter_add_kernel<<<(total + 255) / 256, 256, 0, stream>>>(
            (const float4*)d_in[0], tgt, out);
    }
}

// Round 7
// 94.177 us; speedup vs baseline: 3.9438x; 3.9438x over previous
//
#include <hip/hip_runtime.h>

#define NUM_NODES 10000
#define NUM_EDGES 320000
#define FEAT_DIM  256
#define CAP       64     // bucket slots/node; Poisson(32) => P(deg>64) ~ 1e-7/node
#define OVF_CAP   4096   // overflow (edge,node) pairs; expected 0 used

typedef float f32x4 __attribute__((ext_vector_type(4)));

// ws layout:
//   int cursor[NUM_NODES]     -- per-node degree counters
//   int ovf_cnt               -- overflow counter
//   int ovf[2*OVF_CAP]        -- (edge, node) overflow pairs
//   int buckets[NUM_NODES*CAP]-- per-node edge-id lists (2.56 MB)

// Phase 1: bucket edge ids per target node. 4 edges/thread, vectorized tgt read.
__global__ __launch_bounds__(256) void fill_buckets(
    const int* __restrict__ tgt,
    int*       __restrict__ cursor,
    int*       __restrict__ buckets,
    int*       __restrict__ ovf_cnt,
    int*       __restrict__ ovf)
{
    int base = (blockIdx.x * blockDim.x + threadIdx.x) * 4;
    if (base >= NUM_EDGES) return;                    // NUM_EDGES % 4 == 0
    int4 t4 = *(const int4*)(tgt + base);
    int ts[4] = {t4.x, t4.y, t4.z, t4.w};
    #pragma unroll
    for (int k = 0; k < 4; ++k) {
        int e = base + k;
        int t = ts[k];
        int idx = atomicAdd(&cursor[t], 1);
        if (idx < CAP) {
            buckets[t * CAP + idx] = e;
        } else {
            int o = atomicAdd(ovf_cnt, 1);
            if (o < OVF_CAP) { ovf[2 * o] = e; ovf[2 * o + 1] = t; }
        }
    }
}

// Phase 2: one 64-lane wave per node; lane owns one float4 of the 256-float row.
// Bucket list preloaded lane-parallel (one 256B read), broadcast via __shfl;
// msg rows stream as coalesced 1KB bursts, 8-deep load ILP. Rare deg>CAP edges
// are picked up by scanning the tiny ovf list in-wave (no extra dispatch).
// Writes EVERY row (deg=0 -> zeros), so d_out needs no pre-zeroing.
__global__ __launch_bounds__(256) void gather_sum(
    const f32x4* __restrict__ msg4,
    const int*   __restrict__ cursor,
    const int*   __restrict__ buckets,
    const int*   __restrict__ ovf_cnt,
    const int*   __restrict__ ovf,
    f32x4*       __restrict__ out4)
{
    int g    = threadIdx.x >> 6;          // 4 node-waves per block
    int lane = threadIdx.x & 63;
    int n    = blockIdx.x * 4 + g;
    if (n >= NUM_NODES) return;

    int deg  = cursor[n];
    int m1   = deg < CAP ? deg : CAP;
    const int* bl = buckets + n * CAP;

    f32x4 acc = (f32x4)(0.f);

    int e_l = (lane < m1) ? bl[lane] : 0;
    int i = 0;
    for (; i + 8 <= m1; i += 8) {
        int e0 = __shfl(e_l, i),     e1 = __shfl(e_l, i + 1);
        int e2 = __shfl(e_l, i + 2), e3 = __shfl(e_l, i + 3);
        int e4 = __shfl(e_l, i + 4), e5 = __shfl(e_l, i + 5);
        int e6 = __shfl(e_l, i + 6), e7 = __shfl(e_l, i + 7);
        f32x4 v0 = msg4[(size_t)e0 * 64 + lane];
        f32x4 v1 = msg4[(size_t)e1 * 64 + lane];
        f32x4 v2 = msg4[(size_t)e2 * 64 + lane];
        f32x4 v3 = msg4[(size_t)e3 * 64 + lane];
        f32x4 v4 = msg4[(size_t)e4 * 64 + lane];
        f32x4 v5 = msg4[(size_t)e5 * 64 + lane];
        f32x4 v6 = msg4[(size_t)e6 * 64 + lane];
        f32x4 v7 = msg4[(size_t)e7 * 64 + lane];
        acc += ((v0 + v1) + (v2 + v3)) + ((v4 + v5) + (v6 + v7));
    }
    for (; i + 4 <= m1; i += 4) {
        int e0 = __shfl(e_l, i),     e1 = __shfl(e_l, i + 1);
        int e2 = __shfl(e_l, i + 2), e3 = __shfl(e_l, i + 3);
        f32x4 v0 = msg4[(size_t)e0 * 64 + lane];
        f32x4 v1 = msg4[(size_t)e1 * 64 + lane];
        f32x4 v2 = msg4[(size_t)e2 * 64 + lane];
        f32x4 v3 = msg4[(size_t)e3 * 64 + lane];
        acc += (v0 + v1) + (v2 + v3);
    }
    for (; i < m1; ++i) {
        int e = __shfl(e_l, i);
        acc += msg4[(size_t)e * 64 + lane];
    }

    // Rare overflow path (deg > CAP): this node's extra edges are in ovf.
    if (deg > CAP) {
        int cnt = *ovf_cnt;
        if (cnt > OVF_CAP) cnt = OVF_CAP;
        for (int o = 0; o < cnt; ++o) {
            if (ovf[2 * o + 1] == n) {
                int e = ovf[2 * o];
                acc += msg4[(size_t)e * 64 + lane];
            }
        }
    }

    __builtin_nontemporal_store(acc, out4 + (size_t)n * 64 + lane);
}

// Last-resort fallback if ws is unexpectedly small (round-0 kernel, correct but slow).
__global__ __launch_bounds__(256) void scatter_add_kernel(
    const float4* __restrict__ msg4, const int* __restrict__ tgt, float* __restrict__ out)
{
    int idx = blockIdx.x * blockDim.x + threadIdx.x;
    int e  = idx >> 6;
    int f4 = idx & 63;
    if (e >= NUM_EDGES) return;
    float4 v = msg4[(size_t)e * 64 + f4];
    int t = tgt[e];
    float* o = out + (size_t)t * FEAT_DIM + f4 * 4;
    atomicAdd(o + 0, v.x);
    atomicAdd(o + 1, v.y);
    atomicAdd(o + 2, v.z);
    atomicAdd(o + 3, v.w);
}

extern "C" void kernel_launch(void* const* d_in, const int* in_sizes, int n_in,
                              void* d_out, int out_size, void* d_ws, size_t ws_size,
                              hipStream_t stream) {
    const f32x4* msg4 = (const f32x4*)d_in[0];
    const int*   eidx = (const int*)d_in[1];   // [2, NUM_EDGES] row-major int32
    const int*   tgt  = eidx + NUM_EDGES;      // edge_index[1]
    float*       out  = (float*)d_out;

    const size_t need = ((size_t)NUM_NODES + 1 + 2 * OVF_CAP
                         + (size_t)NUM_NODES * CAP) * sizeof(int);

    if (ws_size >= need) {
        int* cursor  = (int*)d_ws;
        int* ovf_cnt = cursor + NUM_NODES;
        int* ovf     = ovf_cnt + 1;
        int* buckets = ovf + 2 * OVF_CAP;

        // zero cursor + ovf_cnt in one memset (ovf/bucket entries don't need it)
        (void)hipMemsetAsync(cursor, 0, ((size_t)NUM_NODES + 1) * sizeof(int), stream);

        fill_buckets<<<(NUM_EDGES / 4 + 255) / 256, 256, 0, stream>>>(
            tgt, cursor, buckets, ovf_cnt, ovf);
        gather_sum<<<NUM_NODES / 4, 256, 0, stream>>>(
            msg4, cursor, buckets, ovf_cnt, ovf, (f32x4*)out);
    } else {
        (void)hipMemsetAsync(out, 0, (size_t)out_size * sizeof(float), stream);
        const int total = NUM_EDGES * 64;
        scatter_add_kernel<<<(total + 255) / 256, 256, 0, stream>>>(
            (const float4*)d_in[0], tgt, out);
    }
}